// Round 5
// baseline (52.855 us; speedup 1.0000x reference)
//
#include <hip/hip_runtime.h>
#include <hip/hip_bf16.h>

// Fused GCN: one wave (64 lanes) per batch graph; each wave processes NB=2
// consecutive batches software-pipelined (batch j+1's A-tile loads are in
// flight while batch j computes). 4 waves per 256-thread block, no barriers.
// B=16384, V=64, F_IN=5, F_HID=3.
//
// Lane layout: t = (g = t>>4, c = t&15). Iteration i covers row r = 4i+g,
// columns 4c..4c+3 (a[i] = A[r, 4c..4c+3]).

#define V 64
#define WPB 4   // waves per block
#define NB 2    // batches per wave (pipeline depth)

template<int CTRL>
__device__ __forceinline__ float dpp_row_add(float x) {
    // x += x shifted within the aligned 16-lane row; out-of-range lanes add 0.
    int s = __builtin_amdgcn_update_dpp(0, __float_as_int(x), CTRL, 0xF, 0xF, true);
    return x + __int_as_float(s);
}

// Sum over each aligned 16-lane group; result valid on lane 15 of the group.
__device__ __forceinline__ float reduce16(float x) {
    x = dpp_row_add<0x111>(x); // row_shr:1
    x = dpp_row_add<0x112>(x); // row_shr:2
    x = dpp_row_add<0x114>(x); // row_shr:4
    x = dpp_row_add<0x118>(x); // row_shr:8
    return x;
}

// Compute one batch given its A-tile and h0 row in registers.
// Returns the pooled dot-W2 partial (nonzero only on c==15 lanes).
__device__ __forceinline__ float compute_batch(
    const float4* __restrict__ a,    // [16] registers
    const float*  __restrict__ h,    // [5]  registers
    const float* __restrict__ W1, float w20, float w21, float w22,
    float* __restrict__ dinv_row,    // LDS [64] (this wave's slice)
    float* __restrict__ xs0, float* __restrict__ xs1, float* __restrict__ xs2,
    int t, int g, int c)
{
    // ---- rowsum(adj_hat = A + I) -> dinv ----
    #pragma unroll
    for (int i = 0; i < 16; ++i) {
        float p = (a[i].x + a[i].y) + (a[i].z + a[i].w);
        p = reduce16(p);
        if (c == 15) dinv_row[4 * i + g] = rsqrtf(1.0f + p);
    }

    // ---- xs[t,:] = dinv[t] * (h0[t,:] @ W1) ----
    float dv_t = dinv_row[t];               // same-wave LDS dep, no barrier
    float x0 = 0.f, x1 = 0.f, x2 = 0.f;
    #pragma unroll
    for (int k = 0; k < 5; ++k) {
        float hk = h[k];
        x0 += hk * W1[k * 3 + 0];
        x1 += hk * W1[k * 3 + 1];
        x2 += hk * W1[k * 3 + 2];
    }
    xs0[t] = dv_t * x0;
    xs1[t] = dv_t * x1;
    xs2[t] = dv_t * x2;

    // ---- read the 4 xs columns this lane covers, ONCE (reused 16 iters) ----
    float q0[4], q1[4], q2[4];
    #pragma unroll
    for (int j = 0; j < 4; ++j) {
        q0[j] = xs0[4 * c + j];
        q1[j] = xs1[4 * c + j];
        q2[j] = xs2[4 * c + j];
    }
    // identity (A+I): diagonal col of row 4i+g lands on lane c==i, component g
    float xg0 = (g == 0) ? q0[0] : (g == 1) ? q0[1] : (g == 2) ? q0[2] : q0[3];
    float xg1 = (g == 0) ? q1[0] : (g == 1) ? q1[1] : (g == 2) ? q1[2] : q1[3];
    float xg2 = (g == 0) ? q2[0] : (g == 1) ? q2[1] : (g == 2) ? q2[2] : q2[3];

    float total = 0.f;
    #pragma unroll
    for (int i = 0; i < 16; ++i) {
        float p0 = a[i].x * q0[0] + a[i].y * q0[1] + a[i].z * q0[2] + a[i].w * q0[3];
        float p1 = a[i].x * q1[0] + a[i].y * q1[1] + a[i].z * q1[2] + a[i].w * q1[3];
        float p2 = a[i].x * q2[0] + a[i].y * q2[1] + a[i].z * q2[2] + a[i].w * q2[3];
        bool diag = (c == i);
        p0 += diag ? xg0 : 0.f;
        p1 += diag ? xg1 : 0.f;
        p2 += diag ? xg2 : 0.f;
        p0 = reduce16(p0);
        p1 = reduce16(p1);
        p2 = reduce16(p2);
        float dv = dinv_row[4 * i + g];     // broadcast read, no conflict
        float y = fmaxf(dv * p0, 0.f) * w20
                + fmaxf(dv * p1, 0.f) * w21
                + fmaxf(dv * p2, 0.f) * w22;
        total += (c == 15) ? y : 0.f;       // each row counted exactly once
    }
    return total;
}

__global__ __launch_bounds__(64 * WPB, 3) void gcn_fused_kernel(
    const float* __restrict__ A,     // [B, 64, 64]
    const float* __restrict__ h0,    // [B, 64, 5]
    const float* __restrict__ W1,    // [5, 3]
    const float* __restrict__ W2,    // [3, 1]
    float* __restrict__ out)         // [B]
{
    __shared__ float dinv_lds[WPB][V];
    __shared__ float xs_lds[WPB][3][V];

    const int wv = threadIdx.x >> 6;
    const int t  = threadIdx.x & 63;
    const int g  = t >> 4;
    const int c  = t & 15;
    const int b0 = (blockIdx.x * WPB + wv) * NB;   // first batch for this wave

    float* dinv_row = dinv_lds[wv];
    float* xs0 = xs_lds[wv][0];
    float* xs1 = xs_lds[wv][1];
    float* xs2 = xs_lds[wv][2];

    // ---- issue ALL loads for both batches up front; batch1's 16KB stays
    //      in flight while batch0 computes (compiler: s_waitcnt vmcnt(21)) ----
    const float4* A4a = reinterpret_cast<const float4*>(A + (size_t)(b0    ) * (V * V));
    const float4* A4b = reinterpret_cast<const float4*>(A + (size_t)(b0 + 1) * (V * V));
    const float* h0a = h0 + (size_t)(b0    ) * (V * 5) + t * 5;
    const float* h0b = h0 + (size_t)(b0 + 1) * (V * 5) + t * 5;

    float4 aA[16];
    #pragma unroll
    for (int i = 0; i < 16; ++i) aA[i] = A4a[t + 64 * i];
    float hA[5];
    #pragma unroll
    for (int k = 0; k < 5; ++k) hA[k] = h0a[k];

    float4 aB[16];
    #pragma unroll
    for (int i = 0; i < 16; ++i) aB[i] = A4b[t + 64 * i];
    float hB[5];
    #pragma unroll
    for (int k = 0; k < 5; ++k) hB[k] = h0b[k];

    const float w20 = W2[0], w21 = W2[1], w22 = W2[2];

    float tot0 = compute_batch(aA, hA, W1, w20, w21, w22,
                               dinv_row, xs0, xs1, xs2, t, g, c);
    tot0 += __shfl_xor(tot0, 16);
    tot0 += __shfl_xor(tot0, 32);
    if (t == 15) out[b0] = tot0;

    float tot1 = compute_batch(aB, hB, W1, w20, w21, w22,
                               dinv_row, xs0, xs1, xs2, t, g, c);
    tot1 += __shfl_xor(tot1, 16);
    tot1 += __shfl_xor(tot1, 32);
    if (t == 15) out[b0 + 1] = tot1;
}

extern "C" void kernel_launch(void* const* d_in, const int* in_sizes, int n_in,
                              void* d_out, int out_size, void* d_ws, size_t ws_size,
                              hipStream_t stream) {
    const float* A  = (const float*)d_in[0];
    const float* h0 = (const float*)d_in[1];
    const float* W1 = (const float*)d_in[2];
    const float* W2 = (const float*)d_in[3];
    float* out = (float*)d_out;

    const int B = in_sizes[0] / (V * V);             // 16384
    gcn_fused_kernel<<<B / (WPB * NB), 64 * WPB, 0, stream>>>(A, h0, W1, W2, out);
}

// Round 7
// 48.893 us; speedup vs baseline: 1.0810x; 1.0810x over previous
//
#include <hip/hip_runtime.h>
#include <hip/hip_bf16.h>

// Fused GCN: TWO waves per batch graph (each wave owns 32 complete rows),
// 4 waves / 256 threads per block = 2 batches per block. B=16384, V=64.
// A half-tile lives in 8 float4 registers per lane -> target <=64 VGPR
// -> 8 waves/SIMD (32 waves/CU) for maximum memory-latency hiding.
//
// Wave (bl = wave>>1 batch, p = wave&1 row-half). Lane t = (g=t>>4, c=t&15).
// Iteration i covers row r = 32p + 4i + g, columns 4c..4c+3.

#define V 64

template<int CTRL>
__device__ __forceinline__ float dpp_row_add(float x) {
    // x += x shifted within the aligned 16-lane row; out-of-range lanes add 0.
    int s = __builtin_amdgcn_update_dpp(0, __float_as_int(x), CTRL, 0xF, 0xF, true);
    return x + __int_as_float(s);
}

// Sum over each aligned 16-lane group; result valid on lane 15 of the group.
__device__ __forceinline__ float reduce16(float x) {
    x = dpp_row_add<0x111>(x); // row_shr:1
    x = dpp_row_add<0x112>(x); // row_shr:2
    x = dpp_row_add<0x114>(x); // row_shr:4
    x = dpp_row_add<0x118>(x); // row_shr:8
    return x;
}

__global__ __launch_bounds__(256, 8) void gcn_fused_kernel(
    const float* __restrict__ A,     // [B, 64, 64]
    const float* __restrict__ h0,    // [B, 64, 5]
    const float* __restrict__ W1,    // [5, 3]
    const float* __restrict__ W2,    // [3, 1]
    float* __restrict__ out)         // [B]
{
    __shared__ float dinv_lds[2][V];
    __shared__ float xs_lds[2][3][V];
    __shared__ float pool_lds[4];

    const int tid = threadIdx.x;
    const int wv  = tid >> 6;        // wave in block: 0..3
    const int t   = tid & 63;        // lane
    const int bl  = wv >> 1;         // batch within block
    const int p   = wv & 1;          // row-half (rows 32p..32p+31)
    const int g   = t >> 4;
    const int c   = t & 15;
    const int b   = blockIdx.x * 2 + bl;

    // ---- h0 row for this lane's xs work (rows 32p + t, lanes t<32 only).
    //      Issue early; arrives alongside A. ----
    float h[5];
    {
        const float* hr = h0 + ((size_t)b * V + 32 * p + (t & 31)) * 5;
        #pragma unroll
        for (int k = 0; k < 5; ++k) h[k] = hr[k];   // lanes>=32 load harmlessly
    }

    // ---- A half-tile: 8 coalesced float4 loads -> registers (32 VGPR) ----
    const float4* A4 = reinterpret_cast<const float4*>(
        A + (size_t)b * (V * V) + p * (32 * V));
    float4 a[8];
    #pragma unroll
    for (int i = 0; i < 8; ++i) a[i] = A4[t + 64 * i];

    // ---- rowsum(adj_hat = A + I) -> dinv for own 32 rows ----
    #pragma unroll
    for (int i = 0; i < 8; ++i) {
        float s = (a[i].x + a[i].y) + (a[i].z + a[i].w);
        s = reduce16(s);
        if (c == 15) dinv_lds[bl][32 * p + 4 * i + g] = rsqrtf(1.0f + s);
    }

    // ---- xs[w,:] = dinv[w] * (h0[w,:] @ W1) for own rows w = 32p + t, t<32
    //      (same-wave dinv dependency: no barrier needed) ----
    if (t < 32) {
        int w = 32 * p + t;
        float dv = dinv_lds[bl][w];
        float x0 = 0.f, x1 = 0.f, x2 = 0.f;
        #pragma unroll
        for (int k = 0; k < 5; ++k) {
            float hk = h[k];
            x0 += hk * W1[k * 3 + 0];
            x1 += hk * W1[k * 3 + 1];
            x2 += hk * W1[k * 3 + 2];
        }
        xs_lds[bl][0][w] = dv * x0;
        xs_lds[bl][1][w] = dv * x1;
        xs_lds[bl][2][w] = dv * x2;
    }

    __syncthreads();   // xs is consumed cross-wave (both halves read all 64 rows)

    // ---- read the 4 xs columns this lane covers, ONCE (reused 8 iters) ----
    float q0[4], q1[4], q2[4];
    #pragma unroll
    for (int j = 0; j < 4; ++j) {
        q0[j] = xs_lds[bl][0][4 * c + j];
        q1[j] = xs_lds[bl][1][4 * c + j];
        q2[j] = xs_lds[bl][2][4 * c + j];
    }
    // identity (A+I): diagonal col of row r=32p+4i+g -> lane c==8p+i, comp g
    float xg0 = (g == 0) ? q0[0] : (g == 1) ? q0[1] : (g == 2) ? q0[2] : q0[3];
    float xg1 = (g == 0) ? q1[0] : (g == 1) ? q1[1] : (g == 2) ? q1[2] : q1[3];
    float xg2 = (g == 0) ? q2[0] : (g == 1) ? q2[1] : (g == 2) ? q2[2] : q2[3];

    const float w20 = W2[0], w21 = W2[1], w22 = W2[2];
    float total = 0.f;
    #pragma unroll
    for (int i = 0; i < 8; ++i) {
        float p0 = a[i].x * q0[0] + a[i].y * q0[1] + a[i].z * q0[2] + a[i].w * q0[3];
        float p1 = a[i].x * q1[0] + a[i].y * q1[1] + a[i].z * q1[2] + a[i].w * q1[3];
        float p2 = a[i].x * q2[0] + a[i].y * q2[1] + a[i].z * q2[2] + a[i].w * q2[3];
        bool diag = (c == 8 * p + i);
        p0 += diag ? xg0 : 0.f;
        p1 += diag ? xg1 : 0.f;
        p2 += diag ? xg2 : 0.f;
        p0 = reduce16(p0);
        p1 = reduce16(p1);
        p2 = reduce16(p2);
        float dv = dinv_lds[bl][32 * p + 4 * i + g];  // broadcast read
        float y = fmaxf(dv * p0, 0.f) * w20
                + fmaxf(dv * p1, 0.f) * w21
                + fmaxf(dv * p2, 0.f) * w22;
        total += (c == 15) ? y : 0.f;   // each row counted exactly once
    }

    // ---- pool own 32 rows: reduced value lives on the c==15 lanes ----
    total += __shfl_xor(total, 16);
    total += __shfl_xor(total, 32);
    if (t == 15) pool_lds[wv] = total;          // FIX: was t==0 (a zero lane)
    __syncthreads();
    if (p == 0 && t == 0) out[b] = pool_lds[wv] + pool_lds[wv + 1];
}

extern "C" void kernel_launch(void* const* d_in, const int* in_sizes, int n_in,
                              void* d_out, int out_size, void* d_ws, size_t ws_size,
                              hipStream_t stream) {
    const float* A  = (const float*)d_in[0];
    const float* h0 = (const float*)d_in[1];
    const float* W1 = (const float*)d_in[2];
    const float* W2 = (const float*)d_in[3];
    float* out = (float*)d_out;

    const int B = in_sizes[0] / (V * V);          // 16384
    gcn_fused_kernel<<<B / 2, 256, 0, stream>>>(A, h0, W1, W2, out);
}

// Round 8
// 48.537 us; speedup vs baseline: 1.0890x; 1.0073x over previous
//
#include <hip/hip_runtime.h>
#include <hip/hip_bf16.h>

// Fused GCN: TWO waves per batch graph (each wave owns 32 complete rows),
// 2 waves / 128 threads per block = 1 batch per block (minimal sync domain).
// B=16384, V=64. A half-tile: 8 float4 regs/lane, loaded NON-TEMPORAL
// (stream-once data, skip L2/L3 allocation). <=64 VGPR -> 8 waves/SIMD.
//
// Wave p = row-half (rows 32p..32p+31). Lane t = (g=t>>4, c=t&15).
// Iteration i covers row r = 32p + 4i + g, columns 4c..4c+3.

#define V 64

typedef float v4f __attribute__((ext_vector_type(4)));

template<int CTRL>
__device__ __forceinline__ float dpp_row_add(float x) {
    // x += x shifted within the aligned 16-lane row; out-of-range lanes add 0.
    int s = __builtin_amdgcn_update_dpp(0, __float_as_int(x), CTRL, 0xF, 0xF, true);
    return x + __int_as_float(s);
}

// Sum over each aligned 16-lane group; result valid on lane 15 of the group.
__device__ __forceinline__ float reduce16(float x) {
    x = dpp_row_add<0x111>(x); // row_shr:1
    x = dpp_row_add<0x112>(x); // row_shr:2
    x = dpp_row_add<0x114>(x); // row_shr:4
    x = dpp_row_add<0x118>(x); // row_shr:8
    return x;
}

__global__ __launch_bounds__(128, 8) void gcn_fused_kernel(
    const float* __restrict__ A,     // [B, 64, 64]
    const float* __restrict__ h0,    // [B, 64, 5]
    const float* __restrict__ W1,    // [5, 3]
    const float* __restrict__ W2,    // [3, 1]
    float* __restrict__ out)         // [B]
{
    __shared__ float dinv_lds[V];
    __shared__ float xs_lds[3][V];
    __shared__ float pool_lds[2];

    const int tid = threadIdx.x;
    const int p   = tid >> 6;        // wave in block = row-half
    const int t   = tid & 63;        // lane
    const int g   = t >> 4;
    const int c   = t & 15;
    const int b   = blockIdx.x;

    // ---- h0 row for this lane's xs work (rows 32p + (t&31)); nt stream ----
    float h[5];
    {
        const float* hr = h0 + ((size_t)b * V + 32 * p + (t & 31)) * 5;
        #pragma unroll
        for (int k = 0; k < 5; ++k) h[k] = __builtin_nontemporal_load(hr + k);
    }

    // ---- A half-tile: 8 coalesced non-temporal float4 loads -> registers ----
    const v4f* A4 = reinterpret_cast<const v4f*>(
        A + (size_t)b * (V * V) + p * (32 * V));
    v4f a[8];
    #pragma unroll
    for (int i = 0; i < 8; ++i) a[i] = __builtin_nontemporal_load(&A4[t + 64 * i]);

    // ---- rowsum(adj_hat = A + I) -> dinv for own 32 rows ----
    #pragma unroll
    for (int i = 0; i < 8; ++i) {
        float s = (a[i].x + a[i].y) + (a[i].z + a[i].w);
        s = reduce16(s);
        if (c == 15) dinv_lds[32 * p + 4 * i + g] = rsqrtf(1.0f + s);
    }

    // ---- xs[w,:] = dinv[w] * (h0[w,:] @ W1) for own rows w = 32p + t, t<32
    //      (same-wave dinv dependency: no barrier needed) ----
    if (t < 32) {
        int w = 32 * p + t;
        float dv = dinv_lds[w];
        float x0 = 0.f, x1 = 0.f, x2 = 0.f;
        #pragma unroll
        for (int k = 0; k < 5; ++k) {
            float hk = h[k];
            x0 += hk * W1[k * 3 + 0];
            x1 += hk * W1[k * 3 + 1];
            x2 += hk * W1[k * 3 + 2];
        }
        xs_lds[0][w] = dv * x0;
        xs_lds[1][w] = dv * x1;
        xs_lds[2][w] = dv * x2;
    }

    __syncthreads();   // xs is consumed cross-wave (both halves read all 64 rows)

    // ---- read the 4 xs columns this lane covers, ONCE (reused 8 iters) ----
    float q0[4], q1[4], q2[4];
    #pragma unroll
    for (int j = 0; j < 4; ++j) {
        q0[j] = xs_lds[0][4 * c + j];
        q1[j] = xs_lds[1][4 * c + j];
        q2[j] = xs_lds[2][4 * c + j];
    }
    // identity (A+I): diagonal col of row r=32p+4i+g -> lane c==8p+i, comp g
    float xg0 = (g == 0) ? q0[0] : (g == 1) ? q0[1] : (g == 2) ? q0[2] : q0[3];
    float xg1 = (g == 0) ? q1[0] : (g == 1) ? q1[1] : (g == 2) ? q1[2] : q1[3];
    float xg2 = (g == 0) ? q2[0] : (g == 1) ? q2[1] : (g == 2) ? q2[2] : q2[3];

    const float w20 = W2[0], w21 = W2[1], w22 = W2[2];
    float total = 0.f;
    #pragma unroll
    for (int i = 0; i < 8; ++i) {
        float p0 = a[i].x * q0[0] + a[i].y * q0[1] + a[i].z * q0[2] + a[i].w * q0[3];
        float p1 = a[i].x * q1[0] + a[i].y * q1[1] + a[i].z * q1[2] + a[i].w * q1[3];
        float p2 = a[i].x * q2[0] + a[i].y * q2[1] + a[i].z * q2[2] + a[i].w * q2[3];
        bool diag = (c == 8 * p + i);
        p0 += diag ? xg0 : 0.f;
        p1 += diag ? xg1 : 0.f;
        p2 += diag ? xg2 : 0.f;
        p0 = reduce16(p0);
        p1 = reduce16(p1);
        p2 = reduce16(p2);
        float dv = dinv_lds[32 * p + 4 * i + g];  // broadcast read
        float y = fmaxf(dv * p0, 0.f) * w20
                + fmaxf(dv * p1, 0.f) * w21
                + fmaxf(dv * p2, 0.f) * w22;
        total += (c == 15) ? y : 0.f;   // each row counted exactly once
    }

    // ---- pool own 32 rows: reduced value lives on the c==15 lanes ----
    total += __shfl_xor(total, 16);
    total += __shfl_xor(total, 32);
    if (t == 15) pool_lds[p] = total;
    __syncthreads();
    if (tid == 0) out[b] = pool_lds[0] + pool_lds[1];
}

extern "C" void kernel_launch(void* const* d_in, const int* in_sizes, int n_in,
                              void* d_out, int out_size, void* d_ws, size_t ws_size,
                              hipStream_t stream) {
    const float* A  = (const float*)d_in[0];
    const float* h0 = (const float*)d_in[1];
    const float* W1 = (const float*)d_in[2];
    const float* W2 = (const float*)d_in[3];
    float* out = (float*)d_out;

    const int B = in_sizes[0] / (V * V);          // 16384
    gcn_fused_kernel<<<B, 128, 0, stream>>>(A, h0, W1, W2, out);
}